// Round 3
// baseline (203.569 us; speedup 1.0000x reference)
//
#include <hip/hip_runtime.h>
#include <math.h>

#define HH 192
#define WW 320
#define DTOT 507.0f
#define XS 64      // w-span per block
#define TV 64      // v-chunk
#define KD 39      // 3 channels * 13 dy
#define TC 80      // staged slab columns (64 + 12 halo, padded to 80 for float4)
#define TROW 76    // T rows used (w+dx <= 75)
#define TSTR 82    // T column stride: even -> b64-aligned rows; diagonal step 83 (odd)
#define NSPAN 5
#define NCHUNK 5
#define NSEG 190   // diagonal segments per chunk

// ---------- kernel 0: scale = fx * || (r_extri @ inv(l_extri))[:3,3] || ----------
__global__ void prep_kernel(const float* __restrict__ li, const float* __restrict__ le,
                            const float* __restrict__ re, float* __restrict__ ws) {
    if (threadIdx.x != 0 || blockIdx.x != 0) return;
    float a[4][4], inv[4][4];
    for (int i = 0; i < 4; ++i)
        for (int j = 0; j < 4; ++j) { a[i][j] = le[i*4+j]; inv[i][j] = (i == j) ? 1.0f : 0.0f; }
    for (int c = 0; c < 4; ++c) {
        int p = c; float mx = fabsf(a[c][c]);
        for (int r = c+1; r < 4; ++r) { float v = fabsf(a[r][c]); if (v > mx) { mx = v; p = r; } }
        if (p != c) for (int j = 0; j < 4; ++j) {
            float t = a[c][j]; a[c][j] = a[p][j]; a[p][j] = t;
            t = inv[c][j]; inv[c][j] = inv[p][j]; inv[p][j] = t;
        }
        float id = 1.0f / a[c][c];
        for (int j = 0; j < 4; ++j) { a[c][j] *= id; inv[c][j] *= id; }
        for (int r = 0; r < 4; ++r) if (r != c) {
            float f = a[r][c];
            for (int j = 0; j < 4; ++j) { a[r][j] -= f*a[c][j]; inv[r][j] -= f*inv[c][j]; }
        }
    }
    float rel[3];
    for (int i = 0; i < 3; ++i)
        rel[i] = re[i*4+0]*inv[0][3] + re[i*4+1]*inv[1][3] + re[i*4+2]*inv[2][3] + re[i*4+3]*inv[3][3];
    float baseline = sqrtf(rel[0]*rel[0] + rel[1]*rel[1] + rel[2]*rel[2]);
    ws[0] = li[0] * baseline;
}

// ---------- match kernel ----------
__global__ __launch_bounds__(256) void match_kernel(
        const float* __restrict__ limg, const float* __restrict__ rimg,
        const float* __restrict__ ws, float* __restrict__ out) {
    __shared__ float Ls[KD][TC];
    __shared__ float Rs[KD][TC];
    __shared__ float Tt[TROW][TSTR];
    __shared__ float colL[TC];
    __shared__ float colR1[TC];
    __shared__ float colR2[TC];
    __shared__ float smuL[XS];
    __shared__ float2 sMR[TV];                  // (muR, invNormR) per v in chunk
    __shared__ unsigned long long bestKey[XS];  // packed (ordered score, ~v)

    const int span = blockIdx.x;
    const int h    = blockIdx.y;
    const int wlo  = span * XS;
    const int tid  = threadIdx.x;

    // ---- stage left slab (float4 LDS writes, scalar bounds-checked global loads) ----
    for (int q = tid; q < KD*(TC/4); q += 256) {
        int k = q / (TC/4), xq = (q % (TC/4)) * 4;
        int c = k / 13, dy = k % 13;
        int y = h - 6 + dy;
        int x0 = wlo - 6 + xq;
        float4 v = make_float4(0.f, 0.f, 0.f, 0.f);
        if (y >= 0 && y < HH) {
            const float* row = limg + (c*HH + y)*WW;
            if (x0+0 >= 0 && x0+0 < WW) v.x = row[x0+0];
            if (x0+1 >= 0 && x0+1 < WW) v.y = row[x0+1];
            if (x0+2 >= 0 && x0+2 < WW) v.z = row[x0+2];
            if (x0+3 >= 0 && x0+3 < WW) v.w = row[x0+3];
        }
        *(float4*)&Ls[k][xq] = v;
    }
    if (tid < XS) bestKey[tid] = 0ULL;
    __syncthreads();

    // ---- left column sums -> patch means ----
    if (tid < TC) {
        float s = 0.0f;
        for (int k = 0; k < KD; ++k) s += Ls[k][tid];
        colL[tid] = s;
    }
    __syncthreads();
    if (tid < XS) {
        float s = 0.0f;
        #pragma unroll
        for (int dx = 0; dx < 13; ++dx) s += colL[tid + dx];
        smuL[tid] = s / DTOT;
    }
    // smuL visible to Phase B via the chunk-0 barriers below

    for (int ch = 0; ch < NCHUNK; ++ch) {
        const int ulo = ch * TV;

        // ---- stage right slab chunk ----
        for (int q = tid; q < KD*(TC/4); q += 256) {
            int k = q / (TC/4), xq = (q % (TC/4)) * 4;
            int c = k / 13, dy = k % 13;
            int y = h - 6 + dy;
            int u0 = ulo - 6 + xq;
            float4 v = make_float4(0.f, 0.f, 0.f, 0.f);
            if (y >= 0 && y < HH) {
                const float* row = rimg + (c*HH + y)*WW;
                if (u0+0 >= 0 && u0+0 < WW) v.x = row[u0+0];
                if (u0+1 >= 0 && u0+1 < WW) v.y = row[u0+1];
                if (u0+2 >= 0 && u0+2 < WW) v.z = row[u0+2];
                if (u0+3 >= 0 && u0+3 < WW) v.w = row[u0+3];
            }
            *(float4*)&Rs[k][xq] = v;
        }
        __syncthreads();   // s1: Rs ready; prev chunk's Phase-B T-reads done before new T-writes

        // ---- right column sums (s1 & s2) ----
        if (tid < TC) {
            float s1 = 0.0f, s2 = 0.0f;
            for (int k = 0; k < KD; ++k) {
                float v = Rs[k][tid];
                s1 += v;
                s2 = fmaf(v, v, s2);
            }
            colR1[tid] = s1;
            colR2[tid] = s2;
        }

        // ---- Phase A: 8x8 register-tile GEMM, T[i][j] = sum_k Ls[k][i]*Rs[k][j] ----
        if (tid < 100) {
            const int i0 = (tid % 10) * 8;
            const int j0 = (tid / 10) * 8;
            float acc[8][8];
            #pragma unroll
            for (int r = 0; r < 8; ++r)
                #pragma unroll
                for (int c2 = 0; c2 < 8; ++c2) acc[r][c2] = 0.0f;
            for (int k = 0; k < KD; ++k) {
                float4 la0 = *(const float4*)&Ls[k][i0];
                float4 la1 = *(const float4*)&Ls[k][i0+4];
                float4 rb0 = *(const float4*)&Rs[k][j0];
                float4 rb1 = *(const float4*)&Rs[k][j0+4];
                float al[8] = {la0.x, la0.y, la0.z, la0.w, la1.x, la1.y, la1.z, la1.w};
                float bl[8] = {rb0.x, rb0.y, rb0.z, rb0.w, rb1.x, rb1.y, rb1.z, rb1.w};
                #pragma unroll
                for (int r = 0; r < 8; ++r)
                    #pragma unroll
                    for (int c2 = 0; c2 < 8; ++c2)
                        acc[r][c2] = fmaf(al[r], bl[c2], acc[r][c2]);
            }
            #pragma unroll
            for (int r = 0; r < 8; ++r) {
                int i = i0 + r;
                if (i < TROW) {
                    float* dst = &Tt[i][j0];   // (i*82 + j0) even -> 8B aligned
                    #pragma unroll
                    for (int c2 = 0; c2 < 4; ++c2)
                        *(float2*)&dst[c2*2] = make_float2(acc[r][c2*2], acc[r][c2*2+1]);
                }
            }
        }
        __syncthreads();   // s2: T + colR ready

        // ---- per-v stats ----
        if (tid < TV) {
            float s1 = 0.0f, s2 = 0.0f;
            #pragma unroll
            for (int dx = 0; dx < 13; ++dx) { s1 += colR1[tid + dx]; s2 += colR2[tid + dx]; }
            float mu = s1 / DTOT;
            float var = fmaxf(s2 - s1*s1/DTOT, 0.0f);
            sMR[tid] = make_float2(mu, 1.0f / (sqrtf(var) + 1e-5f));
        }
        __syncthreads();   // s3: sMR ready

        // ---- Phase B: diagonal segments, registers hold L+12 taps ----
        if (tid < NSEG) {
            int d, s0, L;
            if (tid < 127) {
                d = tid - 63; s0 = 0;
                int ad = d < 0 ? -d : d;
                int l0 = 64 - ad;
                L = l0 > 32 ? 32 : l0;
            } else {
                d = tid - 158; s0 = 32;
                int ad = d < 0 ? -d : d;
                L = 32 - ad;
            }
            int w0, v0;
            if (d >= 0) { v0 = s0; w0 = s0 + d; } else { w0 = s0; v0 = s0 - d; }
            const float* tf = &Tt[0][0];
            const int base = w0 * TSTR + v0;
            const int maxt = L + 11;
            float tap[44];
            #pragma unroll
            for (int t = 0; t < 44; ++t) {
                int tc = t < maxt ? t : maxt;   // clamp: stay on this diagonal, in-bounds
                tap[t] = tf[base + 83 * tc];
            }
            #pragma unroll
            for (int p = 0; p < 32; ++p) {
                if (p < L) {
                    float S = tap[p];
                    #pragma unroll
                    for (int dx = 1; dx < 13; ++dx) S += tap[p + dx];  // same order as before
                    int w = w0 + p, vcl = v0 + p;
                    float2 mr = sMR[vcl];
                    float score = (S - DTOT * smuL[w] * mr.x) * mr.y;
                    unsigned int su = __float_as_uint(score);
                    su = (su & 0x80000000u) ? ~su : (su | 0x80000000u);
                    unsigned long long key =
                        ((unsigned long long)su << 32) |
                        (unsigned long long)(0xFFFFFFFFu - (unsigned)(ulo + vcl));
                    atomicMax(&bestKey[w], key);
                }
            }
        }
        // next chunk's s1 orders these T-reads before the next T-writes
    }

    __syncthreads();   // all atomics done
    if (tid < XS) {
        unsigned long long key = bestKey[tid];
        int v = (int)(0xFFFFFFFFu - (unsigned)(key & 0xFFFFFFFFu));
        int w = wlo + tid;
        float disp = fabsf((float)v - (float)w);
        disp = fmaxf(disp, 0.001f);
        out[h*WW + w] = ws[0] / disp;
    }
}

extern "C" void kernel_launch(void* const* d_in, const int* in_sizes, int n_in,
                              void* d_out, int out_size, void* d_ws, size_t ws_size,
                              hipStream_t stream) {
    const float* limg   = (const float*)d_in[0];
    const float* rimg   = (const float*)d_in[1];
    const float* lintri = (const float*)d_in[2];
    const float* lex    = (const float*)d_in[4];
    const float* rex    = (const float*)d_in[5];
    float* out = (float*)d_out;
    float* ws  = (float*)d_ws;

    hipLaunchKernelGGL(prep_kernel, dim3(1), dim3(64), 0, stream, lintri, lex, rex, ws);
    hipLaunchKernelGGL(match_kernel, dim3(NSPAN, HH), dim3(256), 0, stream,
                       limg, rimg, ws, out);
}